// Round 1
// baseline (5411.365 us; speedup 1.0000x reference)
//
#include <hip/hip_runtime.h>
#include <hip/hip_bf16.h>
#include <hip/hip_fp16.h>

// Problem dims (fixed by the reference).
#define B_ 256
#define T_ 2048
#define D_ 128

typedef __attribute__((ext_vector_type(8))) short bf16x8;   // MFMA A/B frag (8 bf16)
typedef __attribute__((ext_vector_type(4))) float f32x4;    // MFMA C/D frag
typedef __attribute__((ext_vector_type(4))) unsigned int u32x4;

__device__ __forceinline__ unsigned int bf_rne(float f) {
    unsigned int u = __builtin_bit_cast(unsigned int, f);
    return (u + 0x7FFFu + ((u >> 16) & 1u)) >> 16;
}
__device__ __forceinline__ unsigned int pack_bf2(float lo, float hi) {
    return bf_rne(lo) | (bf_rne(hi) << 16);
}
__device__ __forceinline__ float bf_to_f(unsigned int h) {
    return __builtin_bit_cast(float, h << 16);
}
__device__ __forceinline__ unsigned int pack_h2(float lo, float hi) {
    unsigned int a = (unsigned int)__half_as_ushort(__float2half_rn(lo));
    unsigned int b = (unsigned int)__half_as_ushort(__float2half_rn(hi));
    return a | (b << 16);
}
__device__ __forceinline__ float h_lo(unsigned int g) {
    return __half2float(__ushort_as_half((unsigned short)(g & 0xFFFFu)));
}
__device__ __forceinline__ float h_hi(unsigned int g) {
    return __half2float(__ushort_as_half((unsigned short)(g >> 16)));
}
__device__ __forceinline__ float sigmoid_f(float x) {
    return __builtin_amdgcn_rcpf(1.0f + __expf(-x));
}
__device__ __forceinline__ float tanh_f(float x) {
    return 1.0f - 2.0f * __builtin_amdgcn_rcpf(__expf(2.0f * x) + 1.0f);
}

// Load an A-fragment of a row-major [D][D] fp32 weight matrix as bf16.
// A-layout (16x16x32): lane holds A[m = lane&15][k = (lane>>4)*8 + j], j=0..7.
// Here m = weight row (output index e), k = input index d.
__device__ __forceinline__ bf16x8 load_w_frag(const float* __restrict__ W, int row, int dbase) {
    const float4 a = *(const float4*)(W + row * D_ + dbase);
    const float4 b = *(const float4*)(W + row * D_ + dbase + 4);
    union { bf16x8 v; unsigned int u[4]; } r;
    r.u[0] = pack_bf2(a.x, a.y);
    r.u[1] = pack_bf2(a.z, a.w);
    r.u[2] = pack_bf2(b.x, b.y);
    r.u[3] = pack_bf2(b.z, b.w);
    return r.v;
}

// ---------------------------------------------------------------------------
// Phase 1: P = ev@We^T + be + bp  (fp32 -> d_out, consumed then overwritten by
//          the chain kernel), gates = sigmoid(ev@{Wl,Ww}^T + {bl,bw}) packed as
//          fp16 pairs {leak, write} -> d_ws (u32 per element).
// Block: 512 threads = 8 waves; wave w owns e-slice [16w, 16w+16).
// Tile: 16 rows of ev (rows = b*T + t flattened).
// ---------------------------------------------------------------------------
__global__ __launch_bounds__(512, 4) void proj_kernel(
    const float* __restrict__ ev,
    const float* __restrict__ We, const float* __restrict__ be,
    const float* __restrict__ Wl, const float* __restrict__ bl,
    const float* __restrict__ Ww, const float* __restrict__ bw,
    const float* __restrict__ bp,
    float* __restrict__ P, unsigned int* __restrict__ G)
{
    __shared__ __align__(16) unsigned short evs[16 * 136]; // padded stride: 2-way bank max

    const int tid  = threadIdx.x;
    const int wave = tid >> 6, lane = tid & 63;
    const int l15  = lane & 15, quad = lane >> 4;
    const int ebase = wave << 4;
    const int ecol  = ebase + (quad << 2); // C-layout: e = ebase + quad*4 + reg

    // Register-resident A-frags for the 3 weight matrices.
    bf16x8 aWe[4], aWl[4], aWw[4];
#pragma unroll
    for (int k = 0; k < 4; ++k) {
        const int dbase = k * 32 + quad * 8;
        aWe[k] = load_w_frag(We, ebase + l15, dbase);
        aWl[k] = load_w_frag(Wl, ebase + l15, dbase);
        aWw[k] = load_w_frag(Ww, ebase + l15, dbase);
    }
    float biasP[4], biasL[4], biasW[4];
#pragma unroll
    for (int r = 0; r < 4; ++r) {
        const int e = ecol + r;
        biasP[r] = be[e] + bp[e];  // fold bp into P so the chain adds nothing
        biasL[r] = bl[e];
        biasW[r] = bw[e];
    }

    const int srow = tid >> 5;        // 0..15 staging row
    const int sd   = (tid & 31) << 2; // 0..124 staging d (4 floats)
    const int NT   = (B_ * T_) / 16;  // 32768 row-tiles

    int tile = blockIdx.x;
    float4 stg = {0.f, 0.f, 0.f, 0.f};
    if (tile < NT)
        stg = *(const float4*)(ev + (size_t)(tile * 16 + srow) * D_ + sd);

    for (; tile < NT; tile += gridDim.x) {
        // stage current tile (bf16) into LDS
        *(uint2*)&evs[srow * 136 + sd] =
            make_uint2(pack_bf2(stg.x, stg.y), pack_bf2(stg.z, stg.w));
        __syncthreads();
        // prefetch next tile while computing
        const int nt = tile + gridDim.x;
        if (nt < NT)
            stg = *(const float4*)(ev + (size_t)(nt * 16 + srow) * D_ + sd);

        f32x4 accP = {biasP[0], biasP[1], biasP[2], biasP[3]};
        f32x4 accL = {biasL[0], biasL[1], biasL[2], biasL[3]};
        f32x4 accW = {biasW[0], biasW[1], biasW[2], biasW[3]};
#pragma unroll
        for (int k = 0; k < 4; ++k) {
            // B-layout: lane holds B[k=(lane>>4)*8+j][n=lane&15]; n = batch row
            const bf16x8 bfrag = *(const bf16x8*)&evs[l15 * 136 + k * 32 + quad * 8];
            accP = __builtin_amdgcn_mfma_f32_16x16x32_bf16(aWe[k], bfrag, accP, 0, 0, 0);
            accL = __builtin_amdgcn_mfma_f32_16x16x32_bf16(aWl[k], bfrag, accL, 0, 0, 0);
            accW = __builtin_amdgcn_mfma_f32_16x16x32_bf16(aWw[k], bfrag, accW, 0, 0, 0);
        }
        __syncthreads(); // frag reads done before next tile's LDS write

        // C-layout: col = lane&15 = row-in-tile, row m = quad*4+reg = e (4 consecutive)
        const size_t row_g = (size_t)tile * 16 + l15;
        *(f32x4*)(P + row_g * D_ + ecol) = accP;
        u32x4 gv;
#pragma unroll
        for (int r = 0; r < 4; ++r)
            gv[r] = pack_h2(sigmoid_f(accL[r]), sigmoid_f(accW[r]));
        *(u32x4*)(G + row_g * D_ + ecol) = gv;
    }
}

// ---------------------------------------------------------------------------
// Phase 2: the recurrence. 16 blocks, each owns 16 batch rows; 8 waves per
// block each own a 16-wide e-slice with Wp A-frags in registers. Belief state
// is exchanged each step via LDS as hi/lo-split bf16 (fp32-accurate matvec).
// ---------------------------------------------------------------------------
__global__ __launch_bounds__(512) void chain_kernel(
    const float* __restrict__ Wp,
    const unsigned int* __restrict__ G,
    float* __restrict__ Out)
{
    __shared__ __align__(16) unsigned short bl_hi[2][16 * 136];
    __shared__ __align__(16) unsigned short bl_lo[2][16 * 136];

    const int tid  = threadIdx.x;
    const int wave = tid >> 6, lane = tid & 63;
    const int l15  = lane & 15, quad = lane >> 4;
    const int ebase = wave << 4;
    const int ecol  = ebase + (quad << 2);
    const int b     = (blockIdx.x << 4) + l15; // batch row (C col / B n-index)

    bf16x8 aWp[4];
#pragma unroll
    for (int k = 0; k < 4; ++k)
        aWp[k] = load_w_frag(Wp, ebase + l15, k * 32 + quad * 8);

    const float*        __restrict__ pbase = Out + (size_t)b * T_ * D_ + ecol;
    const unsigned int* __restrict__ gbase = G   + (size_t)b * T_ * D_ + ecol;
    float*              __restrict__ obase = Out + (size_t)b * T_ * D_ + ecol;

    // 2-deep prefetch of P (fp32x4) and packed gates (u32x4)
    f32x4 pf_p[2];
    u32x4 pf_g[2];
    pf_p[0] = *(const f32x4*)(pbase);
    pf_g[0] = *(const u32x4*)(gbase);
    pf_p[1] = *(const f32x4*)(pbase + D_);
    pf_g[1] = *(const u32x4*)(gbase + D_);

    bf16x8 fhi[4], flo[4];
#pragma unroll
    for (int k = 0; k < 4; ++k) { fhi[k] = (bf16x8)0; flo[k] = (bf16x8)0; }
    f32x4 bold = {0.f, 0.f, 0.f, 0.f};

    const int lw_off = l15 * 136 + ecol; // write: my (b-local, e) slots
    const int lr_off = l15 * 136;        // read: B-frag base for my b-local

    for (int t = 0; t < T_; ++t) {
        const int cur = t & 1;
        const int nb  = cur ^ 1; // LDS buffer written this step, read for t+1
        f32x4 acc = pf_p[cur];   // P already includes be+bp
        u32x4 g   = pf_g[cur];
        if (t + 2 < T_) {
            pf_p[cur] = *(const f32x4*)(pbase + (size_t)(t + 2) * D_);
            pf_g[cur] = *(const u32x4*)(gbase + (size_t)(t + 2) * D_);
        }
        // cand_pre = Wp @ belief (hi + lo) + P
#pragma unroll
        for (int k = 0; k < 4; ++k)
            acc = __builtin_amdgcn_mfma_f32_16x16x32_bf16(aWp[k], fhi[k], acc, 0, 0, 0);
#pragma unroll
        for (int k = 0; k < 4; ++k)
            acc = __builtin_amdgcn_mfma_f32_16x16x32_bf16(aWp[k], flo[k], acc, 0, 0, 0);

        f32x4 bnew;
        unsigned int hh[4], ll[4];
#pragma unroll
        for (int r = 0; r < 4; ++r) {
            const float th = tanh_f(acc[r]);
            const float lg = h_lo(g[r]);
            const float wg = h_hi(g[r]);
            const float bn = lg * bold[r] + wg * th;
            bnew[r] = bn;
            const unsigned int h = bf_rne(bn);
            hh[r] = h;
            ll[r] = bf_rne(bn - bf_to_f(h)); // residual for fp32-accurate matvec
        }
        bold = bnew;
        *(f32x4*)(obase + (size_t)t * D_) = bnew; // belief_t -> output (overwrites consumed P)

        *(uint2*)&bl_hi[nb][lw_off] = make_uint2(hh[0] | (hh[1] << 16), hh[2] | (hh[3] << 16));
        *(uint2*)&bl_lo[nb][lw_off] = make_uint2(ll[0] | (ll[1] << 16), ll[2] | (ll[3] << 16));
        __syncthreads();
#pragma unroll
        for (int k = 0; k < 4; ++k) {
            fhi[k] = *(const bf16x8*)&bl_hi[nb][lr_off + k * 32 + quad * 8];
            flo[k] = *(const bf16x8*)&bl_lo[nb][lr_off + k * 32 + quad * 8];
        }
    }
}

extern "C" void kernel_launch(void* const* d_in, const int* in_sizes, int n_in,
                              void* d_out, int out_size, void* d_ws, size_t ws_size,
                              hipStream_t stream)
{
    const float* ev = (const float*)d_in[0];
    const float* We = (const float*)d_in[1];
    const float* be = (const float*)d_in[2];
    const float* Wp = (const float*)d_in[3];
    const float* bp = (const float*)d_in[4];
    const float* Wl = (const float*)d_in[5];
    const float* bl = (const float*)d_in[6];
    const float* Ww = (const float*)d_in[7];
    const float* bw = (const float*)d_in[8];
    float* out = (float*)d_out;
    unsigned int* G = (unsigned int*)d_ws; // needs B*T*D*4 = 256 MiB of workspace
    (void)in_sizes; (void)n_in; (void)out_size; (void)ws_size;

    proj_kernel<<<512, 512, 0, stream>>>(ev, We, be, Wl, bl, Ww, bw, bp, out, G);
    chain_kernel<<<16, 512, 0, stream>>>(Wp, G, out);
}

// Round 2
// 3169.626 us; speedup vs baseline: 1.7073x; 1.7073x over previous
//
#include <hip/hip_runtime.h>
#include <hip/hip_bf16.h>
#include <hip/hip_fp16.h>

// Problem dims (fixed by the reference).
#define B_ 256
#define T_ 2048
#define D_ 128

typedef __attribute__((ext_vector_type(8))) short bf16x8;   // MFMA A/B frag (8 bf16)
typedef __attribute__((ext_vector_type(4))) float f32x4;    // MFMA C/D frag
typedef __attribute__((ext_vector_type(4))) unsigned int u32x4;

__device__ __forceinline__ unsigned int bf_rne(float f) {
    unsigned int u = __builtin_bit_cast(unsigned int, f);
    return (u + 0x7FFFu + ((u >> 16) & 1u)) >> 16;
}
__device__ __forceinline__ unsigned int pack_bf2(float lo, float hi) {
    return bf_rne(lo) | (bf_rne(hi) << 16);
}
__device__ __forceinline__ float bf_to_f(unsigned int h) {
    return __builtin_bit_cast(float, h << 16);
}
__device__ __forceinline__ unsigned int pack_h2(float lo, float hi) {
    unsigned int a = (unsigned int)__half_as_ushort(__float2half_rn(lo));
    unsigned int b = (unsigned int)__half_as_ushort(__float2half_rn(hi));
    return a | (b << 16);
}
__device__ __forceinline__ float h_lo(unsigned int g) {
    return __half2float(__ushort_as_half((unsigned short)(g & 0xFFFFu)));
}
__device__ __forceinline__ float h_hi(unsigned int g) {
    return __half2float(__ushort_as_half((unsigned short)(g >> 16)));
}
__device__ __forceinline__ float sigmoid_f(float x) {
    return __builtin_amdgcn_rcpf(1.0f + __expf(-x));
}
__device__ __forceinline__ float tanh_f(float x) {
    return 1.0f - 2.0f * __builtin_amdgcn_rcpf(__expf(2.0f * x) + 1.0f);
}

// Load an A-fragment of a row-major [D][D] fp32 weight matrix as bf16.
// A-layout (16x16x32): lane holds A[m = lane&15][k = (lane>>4)*8 + j], j=0..7.
__device__ __forceinline__ bf16x8 load_w_frag(const float* __restrict__ W, int row, int dbase) {
    const float4 a = *(const float4*)(W + row * D_ + dbase);
    const float4 b = *(const float4*)(W + row * D_ + dbase + 4);
    union { bf16x8 v; unsigned int u[4]; } r;
    r.u[0] = pack_bf2(a.x, a.y);
    r.u[1] = pack_bf2(a.z, a.w);
    r.u[2] = pack_bf2(b.x, b.y);
    r.u[3] = pack_bf2(b.z, b.w);
    return r.v;
}

// ---------------------------------------------------------------------------
// Phase 1: P = ev@We^T + be + bp (fp32 -> d_out, consumed then overwritten by
//          the chain), gates = sigmoid(ev@{Wl,Ww}^T + {bl,bw}) packed fp16
//          {leak, write} -> d_ws. 512 thr = 8 waves, wave w owns e-slice 16w.
// ---------------------------------------------------------------------------
__global__ __launch_bounds__(512, 4) void proj_kernel(
    const float* __restrict__ ev,
    const float* __restrict__ We, const float* __restrict__ be,
    const float* __restrict__ Wl, const float* __restrict__ bl,
    const float* __restrict__ Ww, const float* __restrict__ bw,
    const float* __restrict__ bp,
    float* __restrict__ P, unsigned int* __restrict__ G)
{
    __shared__ __align__(16) unsigned short evs[16 * 136];

    const int tid  = threadIdx.x;
    const int wave = tid >> 6, lane = tid & 63;
    const int l15  = lane & 15, quad = lane >> 4;
    const int ebase = wave << 4;
    const int ecol  = ebase + (quad << 2);

    bf16x8 aWe[4], aWl[4], aWw[4];
#pragma unroll
    for (int k = 0; k < 4; ++k) {
        const int dbase = k * 32 + quad * 8;
        aWe[k] = load_w_frag(We, ebase + l15, dbase);
        aWl[k] = load_w_frag(Wl, ebase + l15, dbase);
        aWw[k] = load_w_frag(Ww, ebase + l15, dbase);
    }
    float biasP[4], biasL[4], biasW[4];
#pragma unroll
    for (int r = 0; r < 4; ++r) {
        const int e = ecol + r;
        biasP[r] = be[e] + bp[e];
        biasL[r] = bl[e];
        biasW[r] = bw[e];
    }

    const int srow = tid >> 5;
    const int sd   = (tid & 31) << 2;
    const int NT   = (B_ * T_) / 16;

    int tile = blockIdx.x;
    float4 stg = {0.f, 0.f, 0.f, 0.f};
    if (tile < NT)
        stg = *(const float4*)(ev + (size_t)(tile * 16 + srow) * D_ + sd);

    for (; tile < NT; tile += gridDim.x) {
        *(uint2*)&evs[srow * 136 + sd] =
            make_uint2(pack_bf2(stg.x, stg.y), pack_bf2(stg.z, stg.w));
        __syncthreads();
        const int nt = tile + gridDim.x;
        if (nt < NT)
            stg = *(const float4*)(ev + (size_t)(nt * 16 + srow) * D_ + sd);

        f32x4 accP = {biasP[0], biasP[1], biasP[2], biasP[3]};
        f32x4 accL = {biasL[0], biasL[1], biasL[2], biasL[3]};
        f32x4 accW = {biasW[0], biasW[1], biasW[2], biasW[3]};
#pragma unroll
        for (int k = 0; k < 4; ++k) {
            const bf16x8 bfrag = *(const bf16x8*)&evs[l15 * 136 + k * 32 + quad * 8];
            accP = __builtin_amdgcn_mfma_f32_16x16x32_bf16(aWe[k], bfrag, accP, 0, 0, 0);
            accL = __builtin_amdgcn_mfma_f32_16x16x32_bf16(aWl[k], bfrag, accL, 0, 0, 0);
            accW = __builtin_amdgcn_mfma_f32_16x16x32_bf16(aWw[k], bfrag, accW, 0, 0, 0);
        }
        __syncthreads();

        const size_t row_g = (size_t)tile * 16 + l15;
        *(f32x4*)(P + row_g * D_ + ecol) = accP;
        u32x4 gv;
#pragma unroll
        for (int r = 0; r < 4; ++r)
            gv[r] = pack_h2(sigmoid_f(accL[r]), sigmoid_f(accW[r]));
        *(u32x4*)(G + row_g * D_ + ecol) = gv;
    }
}

// ---------------------------------------------------------------------------
// Phase 2: recurrence. 16 blocks x 256 thr (4 waves); each block owns 16 batch
// rows; wave w owns e in [32w, 32w+32) as two 16-wide MFMA acc groups with Wp
// A-frags in registers. Belief exchanged per step via LDS as hi/lo bf16.
// Barrier = raw `s_waitcnt lgkmcnt(0); s_barrier` (LDS visibility only) so the
// t+2 global prefetches and the belief store stay in flight across steps.
// Manual unroll-by-2 keeps all prefetch/frag state in named registers.
// ---------------------------------------------------------------------------
__device__ __forceinline__ void chain_step(
    const bf16x8 (&aW0)[4], const bf16x8 (&aW1)[4],
    bf16x8 (&fhi)[4], bf16x8 (&flo)[4],
    f32x4& P0r, f32x4& P1r, u32x4& G0r, u32x4& G1r,
    f32x4& bold0, f32x4& bold1,
    const float* __restrict__ p0, const float* __restrict__ p1,
    const unsigned int* __restrict__ g0, const unsigned int* __restrict__ g1,
    float* __restrict__ o0, float* __restrict__ o1,
    unsigned short* bhi, unsigned short* blo,   // LDS buffer written this step
    int t, int lw0, int lr, int quad)
{
    f32x4 acc0 = P0r, acc1 = P1r;
    const u32x4 ga = G0r, gb = G1r;
    if (t + 2 < T_) {
        P0r = *(const f32x4*)(p0 + (size_t)(t + 2) * D_);
        P1r = *(const f32x4*)(p1 + (size_t)(t + 2) * D_);
        G0r = *(const u32x4*)(g0 + (size_t)(t + 2) * D_);
        G1r = *(const u32x4*)(g1 + (size_t)(t + 2) * D_);
    }
#pragma unroll
    for (int k = 0; k < 4; ++k) {
        acc0 = __builtin_amdgcn_mfma_f32_16x16x32_bf16(aW0[k], fhi[k], acc0, 0, 0, 0);
        acc1 = __builtin_amdgcn_mfma_f32_16x16x32_bf16(aW1[k], fhi[k], acc1, 0, 0, 0);
    }
#pragma unroll
    for (int k = 0; k < 4; ++k) {
        acc0 = __builtin_amdgcn_mfma_f32_16x16x32_bf16(aW0[k], flo[k], acc0, 0, 0, 0);
        acc1 = __builtin_amdgcn_mfma_f32_16x16x32_bf16(aW1[k], flo[k], acc1, 0, 0, 0);
    }

    f32x4 bn0, bn1;
    unsigned int hh0[4], ll0[4], hh1[4], ll1[4];
#pragma unroll
    for (int r = 0; r < 4; ++r) {
        const float th0 = tanh_f(acc0[r]);
        const float v0  = h_lo(ga[r]) * bold0[r] + h_hi(ga[r]) * th0;
        bn0[r] = v0;
        const unsigned int h0 = bf_rne(v0);
        hh0[r] = h0;
        ll0[r] = bf_rne(v0 - bf_to_f(h0));

        const float th1 = tanh_f(acc1[r]);
        const float v1  = h_lo(gb[r]) * bold1[r] + h_hi(gb[r]) * th1;
        bn1[r] = v1;
        const unsigned int h1 = bf_rne(v1);
        hh1[r] = h1;
        ll1[r] = bf_rne(v1 - bf_to_f(h1));
    }
    bold0 = bn0;
    bold1 = bn1;
    *(f32x4*)(o0 + (size_t)t * D_) = bn0;
    *(f32x4*)(o1 + (size_t)t * D_) = bn1;

    *(uint2*)&bhi[lw0]      = make_uint2(hh0[0] | (hh0[1] << 16), hh0[2] | (hh0[3] << 16));
    *(uint2*)&bhi[lw0 + 16] = make_uint2(hh1[0] | (hh1[1] << 16), hh1[2] | (hh1[3] << 16));
    *(uint2*)&blo[lw0]      = make_uint2(ll0[0] | (ll0[1] << 16), ll0[2] | (ll0[3] << 16));
    *(uint2*)&blo[lw0 + 16] = make_uint2(ll1[0] | (ll1[1] << 16), ll1[2] | (ll1[3] << 16));

    // LDS-only barrier: do NOT drain vmcnt (prefetches/stores stay in flight).
    asm volatile("s_waitcnt lgkmcnt(0)\n\ts_barrier" ::: "memory");

#pragma unroll
    for (int k = 0; k < 4; ++k) {
        fhi[k] = *(const bf16x8*)&bhi[lr + k * 32 + quad * 8];
        flo[k] = *(const bf16x8*)&blo[lr + k * 32 + quad * 8];
    }
}

__global__ __launch_bounds__(256) void chain_kernel(
    const float* __restrict__ Wp,
    const unsigned int* __restrict__ G,
    float* __restrict__ Out)
{
    __shared__ __align__(16) unsigned short bl_hi[2][16 * 136];
    __shared__ __align__(16) unsigned short bl_lo[2][16 * 136];

    const int tid  = threadIdx.x;
    const int wave = tid >> 6, lane = tid & 63;
    const int l15  = lane & 15, quad = lane >> 4;
    const int e0   = (wave << 5) + (quad << 2);   // group-0 C cols
    const int b    = (blockIdx.x << 4) + l15;     // batch row

    bf16x8 aW0[4], aW1[4];
#pragma unroll
    for (int k = 0; k < 4; ++k) {
        const int dbase = k * 32 + quad * 8;
        aW0[k] = load_w_frag(Wp, (wave << 5) + l15, dbase);
        aW1[k] = load_w_frag(Wp, (wave << 5) + 16 + l15, dbase);
    }

    const size_t srow = (size_t)b * T_ * D_;
    const float*        __restrict__ p0 = Out + srow + e0;
    const float*        __restrict__ p1 = Out + srow + e0 + 16;
    const unsigned int* __restrict__ g0 = G   + srow + e0;
    const unsigned int* __restrict__ g1 = G   + srow + e0 + 16;
    float*              __restrict__ o0 = Out + srow + e0;
    float*              __restrict__ o1 = Out + srow + e0 + 16;

    // 2-deep prefetch in NAMED registers (no dynamically-indexed arrays!).
    f32x4 Pa0 = *(const f32x4*)(p0);
    f32x4 Pa1 = *(const f32x4*)(p1);
    u32x4 Ga0 = *(const u32x4*)(g0);
    u32x4 Ga1 = *(const u32x4*)(g1);
    f32x4 Pb0 = *(const f32x4*)(p0 + D_);
    f32x4 Pb1 = *(const f32x4*)(p1 + D_);
    u32x4 Gb0 = *(const u32x4*)(g0 + D_);
    u32x4 Gb1 = *(const u32x4*)(g1 + D_);

    bf16x8 fhi[4], flo[4];
#pragma unroll
    for (int k = 0; k < 4; ++k) { fhi[k] = (bf16x8)0; flo[k] = (bf16x8)0; }
    f32x4 bold0 = {0.f, 0.f, 0.f, 0.f};
    f32x4 bold1 = {0.f, 0.f, 0.f, 0.f};

    const int lw0 = l15 * 136 + e0;
    const int lr  = l15 * 136;

    for (int t = 0; t < T_; t += 2) {
        // even step writes/reads buffer 1, odd step buffer 0
        chain_step(aW0, aW1, fhi, flo, Pa0, Pa1, Ga0, Ga1, bold0, bold1,
                   p0, p1, g0, g1, o0, o1,
                   &bl_hi[1][0], &bl_lo[1][0], t, lw0, lr, quad);
        chain_step(aW0, aW1, fhi, flo, Pb0, Pb1, Gb0, Gb1, bold0, bold1,
                   p0, p1, g0, g1, o0, o1,
                   &bl_hi[0][0], &bl_lo[0][0], t + 1, lw0, lr, quad);
    }
}

extern "C" void kernel_launch(void* const* d_in, const int* in_sizes, int n_in,
                              void* d_out, int out_size, void* d_ws, size_t ws_size,
                              hipStream_t stream)
{
    const float* ev = (const float*)d_in[0];
    const float* We = (const float*)d_in[1];
    const float* be = (const float*)d_in[2];
    const float* Wp = (const float*)d_in[3];
    const float* bp = (const float*)d_in[4];
    const float* Wl = (const float*)d_in[5];
    const float* bl = (const float*)d_in[6];
    const float* Ww = (const float*)d_in[7];
    const float* bw = (const float*)d_in[8];
    float* out = (float*)d_out;
    unsigned int* G = (unsigned int*)d_ws; // B*T*D*4 = 256 MiB of workspace
    (void)in_sizes; (void)n_in; (void)out_size; (void)ws_size;

    proj_kernel<<<1024, 512, 0, stream>>>(ev, We, be, Wl, bl, Ww, bw, bp, out, G);
    chain_kernel<<<16, 256, 0, stream>>>(Wp, G, out);
}